// Round 6
// baseline (386.270 us; speedup 1.0000x reference)
//
#include <hip/hip_runtime.h>

typedef __bf16 bf16x8 __attribute__((ext_vector_type(8)));
typedef float  f32x4  __attribute__((ext_vector_type(4)));

#define TILE   16
#define HALO   22      // TILE + 6
#define KK     7
#define NCLASS 49
#define IMW    256
#define IMH    256
#define HW     65536   // 256*256
#define HH     484     // HALO*HALO
#define KPW    56      // padded n-extent of KP pair table

// ---------------------------------------------------------------------------
// Prep: KP[s][n] = (K[n,s], K[n+7,s])  -> two dwordx2 gathers give all 4 taps
// ---------------------------------------------------------------------------
__global__ void prep_kernel(const float* __restrict__ mk, float2* __restrict__ KP)
{
    for (int i = threadIdx.x; i < NCLASS * KPW; i += 256) {
        int s = i / KPW, n = i - s * KPW;
        float a = (n < NCLASS) ? mk[n * NCLASS + s] : 0.0f;
        float b = (n + KK < NCLASS) ? mk[(n + KK) * NCLASS + s] : 0.0f;
        KP[i] = make_float2(a, b);
    }
}

__global__ __launch_bounds__(256, 2)
void gtnet_kernel(const float* __restrict__ im_input,
                  const float* __restrict__ gt_motion,
                  const float* __restrict__ m_kernel,
                  const float2* __restrict__ KP,
                  float* __restrict__ out_pred,
                  float* __restrict__ out_mask)
{
    // omW: om accumulator (class-major om[n*256+px], thread-private columns,
    // plain RMW), later reused as W (pixel-major W[px*49+t]).
    __shared__ float  omW[NCLASS * 256];              // 50176 B
    __shared__ float4 W4[HH];                         // 7744 B  prepared bilinear products
    __shared__ int    N0[HH];                         // 1936 B  prepared n00 (0 if invalid)
    __shared__ __align__(16) __bf16 KT[64 * 72];      // 9216 B  B-operand K^T, zero-padded
    __shared__ float  iml[3 * HH];                    // 5808 B  im halo
    // total 74880 B -> 2 blocks/CU

    const int tid  = threadIdx.x;
    const int lane = tid & 63, wv_id = tid >> 6;
    const int tx = tid & 15, ty = tid >> 4;
    const int x0 = blockIdx.x * TILE, y0 = blockIdx.y * TILE;
    const int b  = blockIdx.z;
    const int x = x0 + tx, y = y0 + ty;

    // ---------------- phase 1: staging ----------------
    for (int i = tid; i < 64 * 72; i += 256) {
        int t = i / 72, n = i - t * 72;
        float v = (t < NCLASS && n < NCLASS) ? m_kernel[n * NCLASS + t] : 0.0f;
        KT[i] = (__bf16)v;
    }

    const float* mot_x = gt_motion + (size_t)b * 2 * HW;  // channel 0 -> ax
    const float* mot_y = mot_x + HW;                      // channel 1 -> ay
    for (int i = tid; i < HH; i += 256) {
        int hy = i / HALO, hx = i - hy * HALO;
        int gy = y0 - 3 + hy, gx = x0 - 3 + hx;
        float4 w4 = {0.0f, 0.0f, 0.0f, 0.0f};
        int   n00 = 0;
        if (gy >= 0 && gy < IMH && gx >= 0 && gx < IMW) {
            int off = gy * IMW + gx;
            float ay = mot_y[off] + 3.0f;
            float ax = mot_x[off] + 3.0f;
            float iyf = floorf(ay), ixf = floorf(ax);
            float fy = ay - iyf,    fx = ax - ixf;
            float wy0 = 1.0f - fy, wx0 = 1.0f - fx;
            w4.x = wy0 * wx0;  w4.y = wy0 * fx;
            w4.z = fy  * wx0;  w4.w = fy  * fx;
            n00  = (int)iyf * KK + (int)ixf;
        }
        W4[i] = w4;
        N0[i] = n00;
    }

    const float* imP = im_input + ((size_t)b * 6 + 3) * HW;  // last 3 channels
    for (int i = tid; i < 3 * HH; i += 256) {
        int c  = i / HH, r = i - c * HH;
        int hy = r / HALO, hx = r - hy * HALO;
        int gy = y0 - 3 + hy, gx = x0 - 3 + hx;
        float v = 0.0f;
        if (gy >= 0 && gy < IMH && gx >= 0 && gx < IMW)
            v = imP[c * HW + gy * IMW + gx];
        iml[i] = v;
    }

    {   // zero om via float4 stores
        float4* omv = reinterpret_cast<float4*>(omW);
        for (int i = tid; i < NCLASS * 64; i += 256) omv[i] = make_float4(0, 0, 0, 0);
    }

    __syncthreads();

    // ---------------- phase 2: m_mask dense write (own-pixel recompute) ----------
    {
        float ay = mot_y[y * IMW + x] + 3.0f;
        float ax = mot_x[y * IMW + x] + 3.0f;
        float iyf = floorf(ay), ixf = floorf(ax);
        float fy = ay - iyf,    fx = ax - ixf;
        int   iy = (int)iyf,    ix = (int)ixf;
        float wyA[KK], wxB[KK];
        #pragma unroll
        for (int a = 0; a < KK; a++) {
            wyA[a] = (a == iy) ? (1.0f - fy) : ((a == iy + 1) ? fy : 0.0f);
            wxB[a] = (a == ix) ? (1.0f - fx) : ((a == ix + 1) ? fx : 0.0f);
        }
        float* mm = out_mask + (size_t)b * NCLASS * HW + y * IMW + x;
        #pragma unroll
        for (int a = 0; a < KK; a++)
            #pragma unroll
            for (int bb = 0; bb < KK; bb++)
                mm[(size_t)(a * KK + bb) * HW] = wyA[a] * wxB[bb];
    }

    // ---------------- phase 3: om scatter using prepared halo + global K pairs ----
    const int hbase = ty * HALO + tx;
    #pragma unroll
    for (int u = 0; u < KK; u++) {
        #pragma unroll
        for (int v = 0; v < KK; v++) {
            const int s   = u * KK + v;               // compile-time
            const int idx = hbase + u * HALO + v;     // base + compile-time offset
            float4 w  = W4[idx];
            int    n00 = N0[idx];
            float2 kA = KP[s * KPW + n00];            // (k00, k10) via L1
            float2 kB = KP[s * KPW + n00 + 1];        // (k01, k11) via L1
            float* ob = &omW[n00 * 256 + tid];
            ob[0]       += w.x * kA.x;
            ob[256]     += w.y * kB.x;
            ob[7 * 256] += w.z * kA.y;
            ob[8 * 256] += w.w * kB.y;
        }
    }

    __syncthreads();   // om complete

    // ---------------- phase 4: load MFMA fragments ----------------
    bf16x8 af[2][4];   // [kiter][mtile]
    #pragma unroll
    for (int kit = 0; kit < 2; kit++) {
        #pragma unroll
        for (int mt = 0; mt < 4; mt++) {
            int px = wv_id * 64 + mt * 16 + (lane & 15);
            int k0 = kit * 32 + (lane >> 4) * 8;
            bf16x8 a;
            #pragma unroll
            for (int j = 0; j < 8; j++) {
                int n  = k0 + j;
                int nn = (n < NCLASS) ? n : (NCLASS - 1);
                float v = omW[nn * 256 + px];
                a[j] = (__bf16)((n < NCLASS) ? v : 0.0f);
            }
            af[kit][mt] = a;
        }
    }
    bf16x8 bfr[2][4];  // [kiter][ntile]
    #pragma unroll
    for (int kit = 0; kit < 2; kit++) {
        #pragma unroll
        for (int nt = 0; nt < 4; nt++) {
            int t  = nt * 16 + (lane & 15);
            int k0 = kit * 32 + (lane >> 4) * 8;
            bfr[kit][nt] = *reinterpret_cast<const bf16x8*>(&KT[t * 72 + k0]);
        }
    }

    __syncthreads();   // all om reads done before W overwrites the region

    // ---------------- phase 5: MFMA GEMM  W[256x49] = om[256x64] x K^T[64x49pad] ----
    f32x4 acc[4][4];
    #pragma unroll
    for (int mt = 0; mt < 4; mt++) {
        #pragma unroll
        for (int nt = 0; nt < 4; nt++) {
            f32x4 c = {0.0f, 0.0f, 0.0f, 0.0f};
            c = __builtin_amdgcn_mfma_f32_16x16x32_bf16(af[0][mt], bfr[0][nt], c, 0, 0, 0);
            c = __builtin_amdgcn_mfma_f32_16x16x32_bf16(af[1][mt], bfr[1][nt], c, 0, 0, 0);
            acc[mt][nt] = c;
        }
    }

    // writeback: C/D layout col=lane&15 (t), row=(lane>>4)*4+reg (px) -> W[px*49+t]
    #pragma unroll
    for (int mt = 0; mt < 4; mt++) {
        #pragma unroll
        for (int nt = 0; nt < 4; nt++) {
            int t = nt * 16 + (lane & 15);
            if (t < NCLASS) {
                #pragma unroll
                for (int r = 0; r < 4; r++) {
                    int px = wv_id * 64 + mt * 16 + (lane >> 4) * 4 + r;
                    omW[px * NCLASS + t] = acc[mt][nt][r];
                }
            }
        }
    }

    __syncthreads();   // W complete

    // ---------------- phase 6: apply effective 7x7 kernel ----------------
    float wv[NCLASS];
    #pragma unroll
    for (int t = 0; t < NCLASS; t++) wv[t] = omW[tid * NCLASS + t];

    float a0 = 0.0f, a1 = 0.0f, a2 = 0.0f;
    #pragma unroll
    for (int p = 0; p < KK; p++) {
        #pragma unroll
        for (int q = 0; q < KK; q++) {
            float wvv = wv[p * KK + q];
            int   hi = (ty + p) * HALO + (tx + q);
            a0 = fmaf(wvv, iml[hi],          a0);
            a1 = fmaf(wvv, iml[hi + HH],     a1);
            a2 = fmaf(wvv, iml[hi + 2 * HH], a2);
        }
    }
    float* pr = out_pred + (size_t)b * 3 * HW + y * IMW + x;
    pr[0]      = a0;
    pr[HW]     = a1;
    pr[2 * HW] = a2;
}

extern "C" void kernel_launch(void* const* d_in, const int* in_sizes, int n_in,
                              void* d_out, int out_size, void* d_ws, size_t ws_size,
                              hipStream_t stream) {
    const float* im_input  = (const float*)d_in[0];
    // d_in[1] = im_output: unused by the reference computation
    const float* gt_motion = (const float*)d_in[2];
    const float* m_kernel  = (const float*)d_in[3];

    float* pred = (float*)d_out;                        // (16,3,256,256)
    float* mask = pred + (size_t)16 * 3 * HW;           // (16,49,256,256)
    float2* KP  = (float2*)d_ws;                        // 49*56*8 = 21952 B

    hipLaunchKernelGGL(prep_kernel, dim3(1), dim3(256), 0, stream, m_kernel, KP);

    dim3 grid(IMW / TILE, IMH / TILE, 16);
    dim3 block(256);
    hipLaunchKernelGGL(gtnet_kernel, grid, block, 0, stream,
                       im_input, gt_motion, m_kernel, KP, pred, mask);
}

// Round 7
// 355.790 us; speedup vs baseline: 1.0857x; 1.0857x over previous
//
#include <hip/hip_runtime.h>

typedef __bf16 bf16x8 __attribute__((ext_vector_type(8)));
typedef float  f32x4  __attribute__((ext_vector_type(4)));

#define TILE   16
#define HALO   22      // TILE + 6
#define KK     7
#define NCLASS 49
#define IMW    256
#define IMH    256
#define HW     65536   // 256*256
#define HH     484     // HALO*HALO

__global__ __launch_bounds__(256, 2)
void gtnet_kernel(const float* __restrict__ im_input,
                  const float* __restrict__ gt_motion,
                  const float* __restrict__ m_kernel,
                  float* __restrict__ out_pred,
                  float* __restrict__ out_mask)
{
    // omW: om accumulator, layout [half][49][128] (stride 128 so the RMW pairs
    // (n00,n00+1)*128 and (n00+7,n00+8)*128 fuse into ds_read2/write2_b32,
    // offsets 0/128 units <= 255). Columns are thread-private -> plain RMW.
    // Later reused as W (pixel-major W[px*49+t], 12544 floats either way).
    __shared__ float  omW[2 * NCLASS * 128];          // 50176 B
    __shared__ float2 halo[HH];                       // 3872 B (motion ay,ax; sentinel -8)
    __shared__ float  KS[NCLASS * NCLASS];            // 9604 B  KS[s][n] = K[n][s]
    __shared__ __align__(16) __bf16 KT[64 * 72];      // 9216 B (B-operand K^T, zero-padded)
    __shared__ float  iml[3 * HH];                    // 5808 B (im halo)
    // total 78676 B -> 2 blocks/CU

    const int tid  = threadIdx.x;
    const int lane = tid & 63, wv_id = tid >> 6;
    const int tx = tid & 15, ty = tid >> 4;
    const int x0 = blockIdx.x * TILE, y0 = blockIdx.y * TILE;
    const int b  = blockIdx.z;
    const int x = x0 + tx, y = y0 + ty;

    // ---------------- phase 1: staging ----------------
    // KS[s][n] = m_kernel[n][s]  (transposed: the 4-gather is 2 adjacent pairs)
    for (int i = tid; i < NCLASS * NCLASS; i += 256) {
        int s = i / NCLASS, n = i - s * NCLASS;
        KS[i] = m_kernel[n * NCLASS + s];
    }

    for (int i = tid; i < 64 * 72; i += 256) {
        int t = i / 72, n = i - t * 72;
        float v = (t < NCLASS && n < NCLASS) ? m_kernel[n * NCLASS + t] : 0.0f;
        KT[i] = (__bf16)v;
    }

    const float* mot_x = gt_motion + (size_t)b * 2 * HW;  // channel 0 -> ax
    const float* mot_y = mot_x + HW;                      // channel 1 -> ay
    for (int i = tid; i < HH; i += 256) {
        int hy = i / HALO, hx = i - hy * HALO;
        int gy = y0 - 3 + hy, gx = x0 - 3 + hx;
        float2 v;
        if (gy >= 0 && gy < IMH && gx >= 0 && gx < IMW) {
            int off = gy * IMW + gx;
            v.x = mot_y[off] + 3.0f;
            v.y = mot_x[off] + 3.0f;
        } else {
            v.x = -8.0f; v.y = -8.0f;
        }
        halo[i] = v;
    }

    {   // zero om via float4 stores
        float4* omv = reinterpret_cast<float4*>(omW);
        for (int i = tid; i < 2 * NCLASS * 32; i += 256) omv[i] = make_float4(0, 0, 0, 0);
    }

    // issue im halo global loads early (consumed before the om barrier)
    const float* imP = im_input + ((size_t)b * 6 + 3) * HW;  // last 3 channels
    float imreg[6];
    #pragma unroll
    for (int k2 = 0; k2 < 6; k2++) {
        int i = tid + k2 * 256;
        float val = 0.0f;
        if (i < 3 * HH) {
            int c  = i / HH;
            int r  = i - c * HH;
            int hy = r / HALO, hx = r - hy * HALO;
            int gy = y0 - 3 + hy, gx = x0 - 3 + hx;
            if (gy >= 0 && gy < IMH && gx >= 0 && gx < IMW)
                val = imP[c * HW + gy * IMW + gx];
        }
        imreg[k2] = val;
    }

    __syncthreads();

    // ---------------- phase 2: m_mask dense write ----------------
    {
        float2 h = halo[(ty + 3) * HALO + (tx + 3)];
        float iyf = floorf(h.x), ixf = floorf(h.y);
        float fy = h.x - iyf,    fx = h.y - ixf;
        int   iy = (int)iyf,     ix = (int)ixf;
        float wyA[KK], wxB[KK];
        #pragma unroll
        for (int a = 0; a < KK; a++) {
            wyA[a] = (a == iy) ? (1.0f - fy) : ((a == iy + 1) ? fy : 0.0f);
            wxB[a] = (a == ix) ? (1.0f - fx) : ((a == ix + 1) ? fx : 0.0f);
        }
        float* mm = out_mask + (size_t)b * NCLASS * HW + y * IMW + x;
        #pragma unroll
        for (int a = 0; a < KK; a++)
            #pragma unroll
            for (int bb = 0; bb < KK; bb++)
                mm[(size_t)(a * KK + bb) * HW] = wyA[a] * wxB[bb];
    }

    // ---------------- phase 3: om scatter, paired RMW (ds_read2/write2) ----------
    float* const omBase = omW + (tid >> 7) * (NCLASS * 128) + (tid & 127);
    #pragma unroll
    for (int u = 0; u < KK; u++) {
        #pragma unroll
        for (int v = 0; v < KK; v++) {
            const int s = u * KK + v;                  // compile-time
            float2 h = halo[(ty + u) * HALO + (tx + v)];
            float ayc = h.x, axc = h.y;
            float iyf = floorf(ayc), ixf = floorf(axc);
            float fy = ayc - iyf,    fx = ayc >= 0.0f ? (axc - ixf) : 0.0f;
            bool  valid = (ayc >= 0.0f);
            float wy0 = valid ? (1.0f - fy) : 0.0f;
            float wy1 = valid ? fy : 0.0f;
            int   n00 = valid ? ((int)iyf * KK + (int)ixf) : 0;
            const float* kb = &KS[s * NCLASS + n00];   // pairs (0,1) and (7,8)
            float k00 = kb[0];
            float k01 = kb[1];
            float k10 = kb[KK];
            float k11 = kb[KK + 1];
            float wx0 = 1.0f - fx;
            float* ob  = omBase + n00 * 128;
            float* ob7 = ob + 7 * 128;
            // paired loads (ds_read2_b32 offsets 0,128), then paired stores
            float o0 = ob[0],  o1 = ob[128];
            float o7 = ob7[0], o8 = ob7[128];
            ob[0]    = fmaf(wy0 * wx0, k00, o0);
            ob[128]  = fmaf(wy0 * fx , k01, o1);
            ob7[0]   = fmaf(wy1 * wx0, k10, o7);
            ob7[128] = fmaf(wy1 * fx , k11, o8);
        }
    }

    // stage im halo into its LDS region (read much later, after barrier)
    #pragma unroll
    for (int k2 = 0; k2 < 6; k2++) {
        int i = tid + k2 * 256;
        if (i < 3 * HH) iml[i] = imreg[k2];
    }

    __syncthreads();   // om complete

    // ---------------- phase 4: load MFMA fragments ----------------
    bf16x8 af[2][4];   // [kiter][mtile]
    #pragma unroll
    for (int kit = 0; kit < 2; kit++) {
        #pragma unroll
        for (int mt = 0; mt < 4; mt++) {
            int px = wv_id * 64 + mt * 16 + (lane & 15);
            const float* omb = omW + (px >> 7) * (NCLASS * 128) + (px & 127);
            int k0 = kit * 32 + (lane >> 4) * 8;
            bf16x8 a;
            #pragma unroll
            for (int j = 0; j < 8; j++) {
                int n  = k0 + j;
                int nn = (n < NCLASS) ? n : (NCLASS - 1);
                float v = omb[nn * 128];
                a[j] = (__bf16)((n < NCLASS) ? v : 0.0f);
            }
            af[kit][mt] = a;
        }
    }
    bf16x8 bfr[2][4];  // [kiter][ntile]
    #pragma unroll
    for (int kit = 0; kit < 2; kit++) {
        #pragma unroll
        for (int nt = 0; nt < 4; nt++) {
            int t  = nt * 16 + (lane & 15);
            int k0 = kit * 32 + (lane >> 4) * 8;
            bfr[kit][nt] = *reinterpret_cast<const bf16x8*>(&KT[t * 72 + k0]);
        }
    }

    __syncthreads();   // all om reads done before W overwrites the region

    // ---------------- phase 5: MFMA GEMM  W[256x49] = om[256x64] x K^T[64x49pad] ----
    f32x4 acc[4][4];
    #pragma unroll
    for (int mt = 0; mt < 4; mt++) {
        #pragma unroll
        for (int nt = 0; nt < 4; nt++) {
            f32x4 c = {0.0f, 0.0f, 0.0f, 0.0f};
            c = __builtin_amdgcn_mfma_f32_16x16x32_bf16(af[0][mt], bfr[0][nt], c, 0, 0, 0);
            c = __builtin_amdgcn_mfma_f32_16x16x32_bf16(af[1][mt], bfr[1][nt], c, 0, 0, 0);
            acc[mt][nt] = c;
        }
    }

    // writeback: C/D layout col=lane&15 (t), row=(lane>>4)*4+reg (px) -> W[px*49+t]
    #pragma unroll
    for (int mt = 0; mt < 4; mt++) {
        #pragma unroll
        for (int nt = 0; nt < 4; nt++) {
            int t = nt * 16 + (lane & 15);
            if (t < NCLASS) {
                #pragma unroll
                for (int r = 0; r < 4; r++) {
                    int px = wv_id * 64 + mt * 16 + (lane >> 4) * 4 + r;
                    omW[px * NCLASS + t] = acc[mt][nt][r];
                }
            }
        }
    }

    __syncthreads();   // W complete

    // ---------------- phase 6: apply effective 7x7 kernel ----------------
    float wv[NCLASS];
    #pragma unroll
    for (int t = 0; t < NCLASS; t++) wv[t] = omW[tid * NCLASS + t];

    float a0 = 0.0f, a1 = 0.0f, a2 = 0.0f;
    #pragma unroll
    for (int p = 0; p < KK; p++) {
        #pragma unroll
        for (int q = 0; q < KK; q++) {
            float wvv = wv[p * KK + q];
            int   hi = (ty + p) * HALO + (tx + q);
            a0 = fmaf(wvv, iml[hi],          a0);
            a1 = fmaf(wvv, iml[hi + HH],     a1);
            a2 = fmaf(wvv, iml[hi + 2 * HH], a2);
        }
    }
    float* pr = out_pred + (size_t)b * 3 * HW + y * IMW + x;
    pr[0]      = a0;
    pr[HW]     = a1;
    pr[2 * HW] = a2;
}

extern "C" void kernel_launch(void* const* d_in, const int* in_sizes, int n_in,
                              void* d_out, int out_size, void* d_ws, size_t ws_size,
                              hipStream_t stream) {
    const float* im_input  = (const float*)d_in[0];
    // d_in[1] = im_output: unused by the reference computation
    const float* gt_motion = (const float*)d_in[2];
    const float* m_kernel  = (const float*)d_in[3];

    float* pred = (float*)d_out;                        // (16,3,256,256)
    float* mask = pred + (size_t)16 * 3 * HW;           // (16,49,256,256)

    dim3 grid(IMW / TILE, IMH / TILE, 16);
    dim3 block(256);
    hipLaunchKernelGGL(gtnet_kernel, grid, block, 0, stream,
                       im_input, gt_motion, m_kernel, pred, mask);
}